// Round 6
// baseline (935.264 us; speedup 1.0000x reference)
//
#include <hip/hip_runtime.h>
#include <hip/hip_fp16.h>

// CapsuleLayer dynamic routing — round 6: 256-thread blocks, barrier-free loop.
// Diagnosis from rounds 3-5: 640-thread workgroups cap at ~1 resident block/CU
// (occupancy 23-30% regardless of inner structure); ~40 us/round is exposed
// memory latency, not VALU work (~14 us). Fix: lane = (row r, d), thread owns
// ALL 10 j (W frag = 40 VGPR); agreement dot reduced over d by an intra-wave
// butterfly; softmax is then lane-local (no barriers, no LDS in the bi loop).
// s accumulated via LDS ds_add; blocks write partials (no global atomics),
// tiny reduce kernels sum the 36 i-group slices (squash fused into the last).

#define IC 1152
#define IE 8
#define NC 10
#define DV 16
#define NB 256
#define NW (IC * NC * IE * DV)  // 1,474,560
#define BT 8                    // batch elements per block
#define NBG (NB / BT)           // 32
#define NGP 36                  // block covers 32 rows (2 half-tiles of 16)
#define TPB 256
#define SOUT (NC * DV)          // 160
#define SB (NB * SOUT)          // 40,960 floats
#define PART_ELEMS (NGP * NB * SOUT)  // 1,474,560 floats (5.9 MB)

typedef _Float16 h2 __attribute__((ext_vector_type(2)));
union WChunk { int4 v; h2 p[4]; _Float16 h[8]; };

static __device__ inline float fdot2f(h2 a, h2 b, float c) {
#if defined(__has_builtin) && __has_builtin(__builtin_amdgcn_fdot2)
    return __builtin_amdgcn_fdot2(a, b, c, false);
#else
    return fmaf((float)a.x, (float)b.x, fmaf((float)a.y, (float)b.y, c));
#endif
}

// W fp32 [i][j][e][d] -> fp16 chunks Wc[(G2*10 + j)*256 + t], t = i_local*16+d,
// G2 = i>>4, i_local = i&15. Chunk = e=0..7 halves of W[i,j,:,d] (16 B).
// In the round kernel thread t of a half-tile reads chunks [..]*256 + t for
// j=0..9: 256 consecutive chunks per j => perfectly coalesced.
__global__ void wprep_kernel(const float* __restrict__ W, int4* __restrict__ Wc) {
    const int t = blockIdx.x * blockDim.x + threadIdx.x;
    if (t >= NW / 8) return;
    const int tl = t & 255;
    const int rest = t >> 8;
    const int j = rest % NC, G2 = rest / NC;
    const int i = G2 * 16 + (tl >> 4);
    const int d = tl & 15;
    const float* src = W + ((size_t)(i * NC + j) * IE) * DV + d;  // e-stride DV
    WChunk c;
#pragma unroll
    for (int e = 0; e < IE; ++e) c.h[e] = (_Float16)src[(size_t)e * DV];
    Wc[t] = c.v;
}

__global__ void zero_kernel(float4* __restrict__ p) {
    p[blockIdx.x * blockDim.x + threadIdx.x] = make_float4(0.f, 0.f, 0.f, 0.f);
}

template <int R, bool ATOMIC>
__global__ __launch_bounds__(TPB, 4) void round_kernel(
    const float* __restrict__ X,     // [B, IC, IE] fp32
    const int4* __restrict__ Wc,     // coalesced fp16 layout (see wprep)
    const float* __restrict__ bias,  // [IC*NC] fp32
    const float* __restrict__ s0v,   // reduced s from round 0 (R>=1)
    const float* __restrict__ s1v,   // reduced s from round 1 (R==2)
    float* __restrict__ outp)        // partials slice (or s buffer if ATOMIC)
{
    __shared__ float s_lds[BT * SOUT];  // 5 KB block-local s accumulator
    __shared__ float vA[BT * SOUT];     // v1 (R1) or v1+v2 (R2)

    const int Gp = blockIdx.x;  // 0..35  (32-row tile)
    const int bg = blockIdx.y;  // 0..31  (8 batch elements)
    const int tid = threadIdx.x;
    const int d = tid & 15;     // output dim owned by this lane

    // zero the block accumulator
#pragma unroll
    for (int k = 0; k < 5; ++k) s_lds[tid + k * 256] = 0.f;

    if (R >= 1) {
        // fused squash: vA = squash(s0) (+ squash(s1) for R2); 160 threads
        if (tid < BT * 20) {
            const int bi = tid / 20, rem = tid - bi * 20;
            const int jj = rem >> 1, hh = rem & 1;
            const int b = bg * BT + bi;
            const float4* sp = (const float4*)(s0v + (size_t)b * SOUT + jj * DV + hh * 8);
            float4 a0 = sp[0], a1 = sp[1];
            float s8[8] = {a0.x, a0.y, a0.z, a0.w, a1.x, a1.y, a1.z, a1.w};
            float sq = 0.f;
#pragma unroll
            for (int k = 0; k < 8; ++k) sq = fmaf(s8[k], s8[k], sq);
            float sqf = sq + __shfl_xor(sq, 1);
            float sc = sqrtf(sqf) / (1.f + sqf);
            float v8[8];
#pragma unroll
            for (int k = 0; k < 8; ++k) v8[k] = sc * s8[k];
            if (R == 2) {
                const float4* tp = (const float4*)(s1v + (size_t)b * SOUT + jj * DV + hh * 8);
                float4 b0 = tp[0], b1 = tp[1];
                float t8[8] = {b0.x, b0.y, b0.z, b0.w, b1.x, b1.y, b1.z, b1.w};
                float tq = 0.f;
#pragma unroll
                for (int k = 0; k < 8; ++k) tq = fmaf(t8[k], t8[k], tq);
                float tqf = tq + __shfl_xor(tq, 1);
                float tsc = sqrtf(tqf) / (1.f + tqf);
#pragma unroll
                for (int k = 0; k < 8; ++k) v8[k] = fmaf(tsc, t8[k], v8[k]);
            }
#pragma unroll
            for (int k = 0; k < 8; ++k) vA[bi * SOUT + jj * DV + hh * 8 + k] = v8[k];
        }
    }
    __syncthreads();  // s_lds zeroed (+ vA ready) — the only pre-loop barrier

    for (int rc = 0; rc < 2; ++rc) {
        const int G2 = Gp * 2 + rc;
        const int i = G2 * 16 + (tid >> 4);

        // W fragment: all 10 j for this (i, d) — 10 coalesced 16B loads, 40 VGPR
        WChunk w[NC];
        {
            const int4* wp = Wc + (size_t)G2 * NC * 256 + tid;
#pragma unroll
            for (int j = 0; j < NC; ++j) w[j].v = wp[j * 256];
        }
        // bias row: 5 x float2 (i*10 is even => 8B aligned)
        float b10[NC];
        {
            const float2* bp = (const float2*)(bias + (size_t)i * NC);
#pragma unroll
            for (int q = 0; q < 5; ++q) {
                float2 t2 = bp[q];
                b10[2 * q] = t2.x;
                b10[2 * q + 1] = t2.y;
            }
        }
        float c0[NC];
        if (R == 0) {  // c = softmax(bias): b-independent, lane-local
            float Z = 0.f;
#pragma unroll
            for (int j = 0; j < NC; ++j) {
                c0[j] = __expf(b10[j]);
                Z += c0[j];
            }
            float rz = __builtin_amdgcn_rcpf(Z);
#pragma unroll
            for (int j = 0; j < NC; ++j) c0[j] *= rz;
        }

        for (int bi = 0; bi < BT; ++bi) {
            const int b = bg * BT + bi;

            const float4* xr = (const float4*)(X + ((size_t)b * IC + i) * IE);
            float4 x0 = xr[0], x1 = xr[1];
            h2 x2[4];
            x2[0] = h2{(_Float16)x0.x, (_Float16)x0.y};
            x2[1] = h2{(_Float16)x0.z, (_Float16)x0.w};
            x2[2] = h2{(_Float16)x1.x, (_Float16)x1.y};
            x2[3] = h2{(_Float16)x1.z, (_Float16)x1.w};

            // hat[j] = hat[b,i,j,d]
            float hat[NC];
#pragma unroll
            for (int j = 0; j < NC; ++j) {
                float a = 0.f;
#pragma unroll
                for (int q = 0; q < 4; ++q) a = fdot2f(x2[q], w[j].p[q], a);
                hat[j] = a;
            }

            float cj[NC];
            if (R >= 1) {
                // agreement: per-d partial, butterfly over the 16 d-lanes
                float a[NC];
#pragma unroll
                for (int j = 0; j < NC; ++j) a[j] = hat[j] * vA[bi * SOUT + j * DV + d];
#pragma unroll
                for (int m = 1; m <= 8; m <<= 1) {
#pragma unroll
                    for (int j = 0; j < NC; ++j) a[j] += __shfl_xor(a[j], m);
                }
                // lane-local softmax (logits bounded ~±5; no max-subtract)
                float Z = 0.f;
#pragma unroll
                for (int j = 0; j < NC; ++j) {
                    cj[j] = __expf(b10[j] + a[j]);
                    Z += cj[j];
                }
                float rz = __builtin_amdgcn_rcpf(Z);
#pragma unroll
                for (int j = 0; j < NC; ++j) cj[j] *= rz;
            } else {
#pragma unroll
                for (int j = 0; j < NC; ++j) cj[j] = c0[j];
            }

            // s[b,j,d] += c*hat ; 4 row-lanes share each address (ds_add)
#pragma unroll
            for (int j = 0; j < NC; ++j)
                atomicAdd(&s_lds[bi * SOUT + j * DV + d], cj[j] * hat[j]);
        }
    }

    __syncthreads();

    if (ATOMIC) {
        float* sp = outp + (size_t)bg * BT * SOUT;
#pragma unroll
        for (int k = 0; k < 5; ++k) {
            const int slot = tid + k * 256;
            atomicAdd(&sp[slot], s_lds[slot]);
        }
    } else {
        float* pp = outp + (size_t)Gp * (size_t)NB * SOUT + (size_t)bg * BT * SOUT;
#pragma unroll
        for (int k = 0; k < 5; ++k) {
            const int slot = tid + k * 256;
            pp[slot] = s_lds[slot];
        }
    }
}

// sum the 36 partial slices; optionally apply squash (final round -> out)
template <bool SQ>
__global__ __launch_bounds__(256) void reduce_kernel(const float* __restrict__ part,
                                                     float* __restrict__ outp) {
    const int idx = blockIdx.x * 256 + threadIdx.x;  // < 40960
    float v = 0.f;
#pragma unroll
    for (int g = 0; g < NGP; ++g) v += part[(size_t)g * SB + idx];
    if (SQ) {
        float sq = v * v;
#pragma unroll
        for (int mk = 1; mk <= 8; mk <<= 1) sq += __shfl_xor(sq, mk);
        float sc = sqrtf(sq) / (1.f + sq);
        outp[idx] = sc * v;
    } else {
        outp[idx] = v;
    }
}

__global__ __launch_bounds__(192) void squash_kernel(const float* __restrict__ s_ws,
                                                     float* __restrict__ vout) {
    const int b = blockIdx.x, t = threadIdx.x;
    if (t < SOUT) {
        float sv = s_ws[(size_t)b * SOUT + t];
        float s2 = sv * sv;
#pragma unroll
        for (int mk = 8; mk >= 1; mk >>= 1) s2 += __shfl_xor(s2, mk, 16);
        float scale = sqrtf(s2) / (1.f + s2);
        vout[(size_t)b * SOUT + t] = scale * sv;
    }
}

extern "C" void kernel_launch(void* const* d_in, const int* in_sizes, int n_in,
                              void* d_out, int out_size, void* d_ws, size_t ws_size,
                              hipStream_t stream) {
    const float* X = (const float*)d_in[0];     // [256,1152,8]
    const float* W = (const float*)d_in[1];     // [1152,10,8,16]
    const float* bias = (const float*)d_in[2];  // [1,1152,10]
    float* out = (float*)d_out;

    float* base = (float*)d_ws;
    int4* Wc = (int4*)d_ws;

    const size_t need_part = (size_t)(NW / 2 + PART_ELEMS + 2 * SB) * sizeof(float);  // ~9.2 MB
    dim3 rg(NGP, NBG);  // (36, 32)

    wprep_kernel<<<dim3(720), dim3(256), 0, stream>>>(W, Wc);

    if (ws_size >= need_part) {
        // primary: partial-sum buffers, no global atomics
        float* part = base + NW / 2;
        float* s0 = part + PART_ELEMS;
        float* s1 = s0 + SB;
        round_kernel<0, false><<<rg, TPB, 0, stream>>>(X, Wc, bias, nullptr, nullptr, part);
        reduce_kernel<false><<<dim3(160), dim3(256), 0, stream>>>(part, s0);
        round_kernel<1, false><<<rg, TPB, 0, stream>>>(X, Wc, bias, s0, nullptr, part);
        reduce_kernel<false><<<dim3(160), dim3(256), 0, stream>>>(part, s1);
        round_kernel<2, false><<<rg, TPB, 0, stream>>>(X, Wc, bias, s0, s1, part);
        reduce_kernel<true><<<dim3(160), dim3(256), 0, stream>>>(part, out);
    } else {
        // fallback: global atomics into s buffers (ws ~3.4 MB)
        float* s0 = base + NW / 2;
        float* s1 = s0 + SB;
        float* s2 = s1 + SB;
        zero_kernel<<<dim3(120), dim3(256), 0, stream>>>((float4*)s0);  // s0..s2
        round_kernel<0, true><<<rg, TPB, 0, stream>>>(X, Wc, bias, nullptr, nullptr, s0);
        round_kernel<1, true><<<rg, TPB, 0, stream>>>(X, Wc, bias, s0, nullptr, s1);
        round_kernel<2, true><<<rg, TPB, 0, stream>>>(X, Wc, bias, s0, s1, s2);
        squash_kernel<<<NB, 192, 0, stream>>>(s2, out);
    }
}

// Round 8
// 283.445 us; speedup vs baseline: 3.2996x; 3.2996x over previous
//
#include <hip/hip_runtime.h>
#include <hip/hip_fp16.h>

// CapsuleLayer dynamic routing — round 7b: stall-free inner loop (compile fix:
// bit_cast the __fp16-vector result of cvt_pkrtz to our _Float16 vector type).
// Evidence R3-R6: VALU work is ~13 us/round; everything above it is exposed
// global-load latency in the bi loop (barriers and DS were exonerated by the
// R4/R5 A-B). Fix: prefetch ALL of this block's X into registers (packed fp16
// via cvt_pkrtz, BT=4 -> 16 VGPR) so the routing loop touches no global
// memory. s-reduction: 7-shuffle octet butterfly + one 4-way LDS ds_add per
// bi. BT=4 -> grid (36,64)=2304 blocks (9/CU queued), VGPR ~92 -> 2 resident.

#define IC 1152
#define IE 8
#define NC 10
#define DV 16
#define NB 256
#define NW (IC * NC * IE * DV)  // 1,474,560
#define BT 4                    // batch elements per block (X prefetch = 16 VGPR)
#define NBG (NB / BT)           // 64
#define NGP (IC / 32)           // 36
#define TPB 640                 // wave w <-> output capsule j=w
#define SOUT (NC * DV)          // 160
#define SB (NB * SOUT)          // 40,960 floats per s buffer

typedef _Float16 h2 __attribute__((ext_vector_type(2)));
union WChunk { int4 v; h2 p[4]; _Float16 h[8]; };

static __device__ inline float fdot2f(h2 a, h2 b, float c) {
#if defined(__has_builtin) && __has_builtin(__builtin_amdgcn_fdot2)
    return __builtin_amdgcn_fdot2(a, b, c, false);
#else
    return fmaf((float)a.x, (float)b.x, fmaf((float)a.y, (float)b.y, c));
#endif
}

static __device__ inline h2 pkrtz(float a, float b) {
#if defined(__has_builtin) && __has_builtin(__builtin_amdgcn_cvt_pkrtz)
    return __builtin_bit_cast(h2, __builtin_amdgcn_cvt_pkrtz(a, b));
#else
    return h2{(_Float16)a, (_Float16)b};
#endif
}

// W fp32 [i][j][e][d] -> fp16 chunks Wc[((Gp*10+j)*8+k)*64 + lane], where
// lane = h*32+r, i = Gp*32+r, d = h*8+k; chunk holds e=0..7 halves of W[i,j,:,d].
__global__ void wprep_kernel(const float* __restrict__ W, int4* __restrict__ Wc) {
    const int t = blockIdx.x * blockDim.x + threadIdx.x;
    if (t >= NW / 8) return;
    const int lane = t & 63;
    const int h = lane >> 5, r = lane & 31;
    const int k = (t >> 6) & 7;
    const int r2 = t >> 9;  // Gp*10 + j
    const int j = r2 % NC, Gp = r2 / NC;
    const int i = Gp * 32 + r;
    const int d = h * 8 + k;
    const float* src = W + ((size_t)(i * NC + j) * IE) * DV + d;  // e-stride DV
    WChunk c;
#pragma unroll
    for (int e = 0; e < IE; ++e) c.h[e] = (_Float16)src[(size_t)e * DV];
    Wc[t] = c.v;
}

__global__ void zero_kernel(float4* __restrict__ p) {
    p[blockIdx.x * blockDim.x + threadIdx.x] = make_float4(0.f, 0.f, 0.f, 0.f);
}

template <int R>
__global__ __launch_bounds__(TPB, 5) void round_kernel(
    const float* __restrict__ X,     // [B, IC, IE] fp32
    const int4* __restrict__ Wc,     // coalesced fp16 layout (see wprep)
    const float* __restrict__ bias,  // [IC*NC] fp32
    const float* __restrict__ s0v,   // reduced s from round 0 (R>=1)
    const float* __restrict__ s1v,   // reduced s from round 1 (R==2)
    float* __restrict__ s_out)       // [B*160] accumulated via atomics
{
    __shared__ float vA[BT * SOUT];     // 640: v1 (R1) or v1+v2 (R2)
    __shared__ float s_lds[BT * SOUT];  // 640: block-local s accumulator
    __shared__ float Zb[3][32];         // triple-buffered per-row sum(exp)
    __shared__ float Z0[32];            // round-0 Z

    const int Gp = blockIdx.x;  // 0..35
    const int bg = blockIdx.y;  // 0..63
    const int tid = threadIdx.x;
    const int j = tid >> 6;     // wave = output capsule
    const int g = tid & 63;
    const int h = g >> 5;       // d-half: d = h*8 + k
    const int r = g & 31;       // row within group
    const int i = Gp * 32 + r;

    // ---- prefetch phase: all global loads happen here ----
    // W fragment: 8 int4 (32 VGPR), lane-consecutive => coalesced
    WChunk w[8];
    {
        const int4* wp = Wc + ((size_t)(Gp * NC + j) * 8) * 64 + g;
#pragma unroll
        for (int k = 0; k < 8; ++k) w[k].v = wp[k * 64];
    }
    // X rows for all BT batch elements, packed fp16 (16 VGPR)
    h2 xh[BT][4];
#pragma unroll
    for (int bi = 0; bi < BT; ++bi) {
        const int b = bg * BT + bi;
        const float4* xr = (const float4*)(X + ((size_t)b * IC + i) * IE);
        float4 x0 = xr[0], x1 = xr[1];
        xh[bi][0] = pkrtz(x0.x, x0.y);
        xh[bi][1] = pkrtz(x0.z, x0.w);
        xh[bi][2] = pkrtz(x1.x, x1.y);
        xh[bi][3] = pkrtz(x1.z, x1.w);
    }
    const float lt_bias = bias[i * NC + j];

    // ---- LDS init + fused squash of previous round's s ----
    s_lds[tid] = 0.f;
    if (tid < 96) ((float*)Zb)[tid] = 0.f;
    if (R == 0 && tid < 32) Z0[tid] = 0.f;
    if (R >= 1 && tid < BT * 20) {
        const int bi = tid / 20, rem = tid - bi * 20;
        const int jj = rem >> 1, hh = rem & 1;
        const int b = bg * BT + bi;
        const float4* sp = (const float4*)(s0v + (size_t)b * SOUT + jj * DV + hh * 8);
        float4 a0 = sp[0], a1 = sp[1];
        float s8[8] = {a0.x, a0.y, a0.z, a0.w, a1.x, a1.y, a1.z, a1.w};
        float sq = 0.f;
#pragma unroll
        for (int k = 0; k < 8; ++k) sq = fmaf(s8[k], s8[k], sq);
        float sqf = sq + __shfl_xor(sq, 1);
        float sc = sqrtf(sqf) / (1.f + sqf);
        float v8[8];
#pragma unroll
        for (int k = 0; k < 8; ++k) v8[k] = sc * s8[k];
        if (R == 2) {
            const float4* tp = (const float4*)(s1v + (size_t)b * SOUT + jj * DV + hh * 8);
            float4 b0 = tp[0], b1 = tp[1];
            float t8[8] = {b0.x, b0.y, b0.z, b0.w, b1.x, b1.y, b1.z, b1.w};
            float tq = 0.f;
#pragma unroll
            for (int k = 0; k < 8; ++k) tq = fmaf(t8[k], t8[k], tq);
            float tqf = tq + __shfl_xor(tq, 1);
            float tsc = sqrtf(tqf) / (1.f + tqf);
#pragma unroll
            for (int k = 0; k < 8; ++k) v8[k] = fmaf(tsc, t8[k], v8[k]);
        }
#pragma unroll
        for (int k = 0; k < 8; ++k) vA[bi * SOUT + jj * DV + hh * 8 + k] = v8[k];
    }
    __syncthreads();

    float c0 = 0.f;
    if (R == 0) {  // round 0: c = softmax(bias), b-independent, hoisted
        const float ex0 = __expf(lt_bias);
        if (h == 0) atomicAdd(&Z0[r], ex0);
        __syncthreads();
        c0 = ex0 * __builtin_amdgcn_rcpf(Z0[r]);
    }

    // ---- routing loop: no global memory, ~12 DS ops per iteration ----
    for (int bi = 0; bi < BT; ++bi) {
        float hat[8];
#pragma unroll
        for (int k = 0; k < 8; ++k) {
            float a = 0.f;
#pragma unroll
            for (int q = 0; q < 4; ++q) a = fdot2f(xh[bi][q], w[k].p[q], a);
            hat[k] = a;
        }

        float c;
        if (R >= 1) {
            const float4* vp = (const float4*)&vA[bi * SOUT + j * DV + h * 8];
            float4 va = vp[0], vb = vp[1];
            const float vv[8] = {va.x, va.y, va.z, va.w, vb.x, vb.y, vb.z, vb.w};
            float ah = 0.f;
#pragma unroll
            for (int k = 0; k < 8; ++k) ah = fmaf(hat[k], vv[k], ah);
            const float lt = lt_bias + ah + __shfl_xor(ah, 32);
            const float ex = __expf(lt);
            if (h == 0) atomicAdd(&Zb[bi % 3][r], ex);
            if (tid >= 64 && tid < 96) Zb[(bi + 1) % 3][tid & 31] = 0.f;
            __syncthreads();
            c = ex * __builtin_amdgcn_rcpf(Zb[bi % 3][r]);
        } else {
            c = c0;  // no barrier, no DS
        }

        float s8[8];
#pragma unroll
        for (int k = 0; k < 8; ++k) s8[k] = c * hat[k];

        // octet splitting butterfly: 8 values over 8 r-lanes -> lane q holds k=q
        float t4[4];
#pragma unroll
        for (int m = 0; m < 4; ++m) {
            const bool hi = (r & 4) != 0;
            float mine = hi ? s8[m + 4] : s8[m];
            float send = hi ? s8[m] : s8[m + 4];
            t4[m] = mine + __shfl_xor(send, 4);
        }
        float t2[2];
#pragma unroll
        for (int m = 0; m < 2; ++m) {
            const bool hi = (r & 2) != 0;
            float mine = hi ? t4[m + 2] : t4[m];
            float send = hi ? t4[m] : t4[m + 2];
            t2[m] = mine + __shfl_xor(send, 2);
        }
        float t1;
        {
            const bool hi = (r & 1) != 0;
            float mine = hi ? t2[1] : t2[0];
            float send = hi ? t2[0] : t2[1];
            t1 = mine + __shfl_xor(send, 1);
        }
        // 4 octets add to the same (bi,j,d) slot: 4-way ds_add
        atomicAdd(&s_lds[bi * SOUT + j * DV + h * 8 + (r & 7)], t1);
    }

    __syncthreads();
    // one global atomic per thread (s_lds has exactly TPB=640 entries)
    const int bo = tid / SOUT, slot = tid % SOUT;
    atomicAdd(&s_out[(size_t)(bg * BT + bo) * SOUT + slot], s_lds[tid]);
}

__global__ __launch_bounds__(192) void squash_kernel(const float* __restrict__ s_ws,
                                                     float* __restrict__ vout) {
    const int b = blockIdx.x, t = threadIdx.x;
    if (t < SOUT) {
        float sv = s_ws[(size_t)b * SOUT + t];
        float s2 = sv * sv;
#pragma unroll
        for (int mk = 8; mk >= 1; mk >>= 1) s2 += __shfl_xor(s2, mk, 16);
        float scale = sqrtf(s2) / (1.f + s2);
        vout[(size_t)b * SOUT + t] = scale * sv;
    }
}

extern "C" void kernel_launch(void* const* d_in, const int* in_sizes, int n_in,
                              void* d_out, int out_size, void* d_ws, size_t ws_size,
                              hipStream_t stream) {
    const float* X = (const float*)d_in[0];     // [256,1152,8]
    const float* W = (const float*)d_in[1];     // [1152,10,8,16]
    const float* bias = (const float*)d_in[2];  // [1,1152,10]
    float* out = (float*)d_out;

    // ws (floats): Wc (NW/2) | s0 | s1 | s2   = ~3.4 MB (same as round 5, known OK)
    float* base = (float*)d_ws;
    int4* Wc = (int4*)d_ws;
    float* s0 = base + NW / 2;
    float* s1 = s0 + SB;
    float* s2 = s1 + SB;

    wprep_kernel<<<dim3(720), dim3(256), 0, stream>>>(W, Wc);
    zero_kernel<<<dim3(120), dim3(256), 0, stream>>>((float4*)s0);  // s0,s1,s2

    dim3 rg(NGP, NBG);  // (36, 64)
    round_kernel<0><<<rg, TPB, 0, stream>>>(X, Wc, bias, nullptr, nullptr, s0);
    round_kernel<1><<<rg, TPB, 0, stream>>>(X, Wc, bias, s0, nullptr, s1);   // v1 fused
    round_kernel<2><<<rg, TPB, 0, stream>>>(X, Wc, bias, s0, s1, s2);        // v1+v2 fused
    squash_kernel<<<NB, 192, 0, stream>>>(s2, out);
}